// Round 1
// baseline (2316.713 us; speedup 1.0000x reference)
//
#include <hip/hip_runtime.h>
#include <math.h>

#define NN 100000
#define NE 3200000
#define FD 256        // feature dim
#define NC 40         // classes

// ---------------- CSR build ----------------

__global__ __launch_bounds__(256) void edge_hist(const int* __restrict__ ei, int* __restrict__ counts) {
    int i = blockIdx.x * 256 + threadIdx.x;
    if (i < NE) {
        int d = ei[NE + i];
        atomicAdd(&counts[d], 1);
    }
}

__global__ __launch_bounds__(256) void chunk_sum(const int* __restrict__ counts, int* __restrict__ chunk_sums) {
    __shared__ int sh[256];
    int t = threadIdx.x;
    int i = blockIdx.x * 256 + t;
    int v = (i < NN) ? counts[i] : 0;
    sh[t] = v;
    __syncthreads();
    for (int d = 128; d > 0; d >>= 1) {
        if (t < d) sh[t] += sh[t + d];
        __syncthreads();
    }
    if (t == 0) chunk_sums[blockIdx.x] = sh[0];
}

// single block, 512 threads: exclusive scan of NCHUNK (<512) chunk sums in place
__global__ __launch_bounds__(512) void scan_chunks(int* __restrict__ chunk_sums, int nchunk, int* __restrict__ row_ptr) {
    __shared__ int s[512];
    int t = threadIdx.x;
    int v = (t < nchunk) ? chunk_sums[t] : 0;
    s[t] = v;
    __syncthreads();
    for (int d = 1; d < 512; d <<= 1) {
        int x = (t >= d) ? s[t - d] : 0;
        __syncthreads();
        s[t] += x;
        __syncthreads();
    }
    if (t < nchunk) chunk_sums[t] = s[t] - v;   // exclusive
    if (t == 0) row_ptr[NN] = NE;
}

// per-chunk exclusive scan + chunk offset; counts lives in wptr, overwritten with start positions
__global__ __launch_bounds__(256) void block_scan(int* __restrict__ wptr, const int* __restrict__ chunk_sums,
                                                  int* __restrict__ row_ptr) {
    __shared__ int s[256];
    int t = threadIdx.x;
    int i = blockIdx.x * 256 + t;
    int v = (i < NN) ? wptr[i] : 0;
    s[t] = v;
    __syncthreads();
    for (int d = 1; d < 256; d <<= 1) {
        int x = (t >= d) ? s[t - d] : 0;
        __syncthreads();
        s[t] += x;
        __syncthreads();
    }
    int excl = s[t] - v + chunk_sums[blockIdx.x];
    if (i < NN) {
        row_ptr[i] = excl;
        wptr[i] = excl;
    }
}

__global__ __launch_bounds__(256) void edge_scatter(const int* __restrict__ ei, const float* __restrict__ ev,
                                                    int* __restrict__ wptr,
                                                    int* __restrict__ csr_src, float* __restrict__ csr_val) {
    int i = blockIdx.x * 256 + threadIdx.x;
    if (i < NE) {
        int s = ei[i];
        int d = ei[NE + i];
        int p = atomicAdd(&wptr[d], 1);
        csr_src[p] = s;
        csr_val[p] = ev[i];
    }
}

// ---------------- SPMM: one wave per dst row, float4 per lane ----------------

__global__ __launch_bounds__(256) void spmm(const int* __restrict__ row_ptr,
                                            const int* __restrict__ csr_src,
                                            const float* __restrict__ csr_val,
                                            const float* __restrict__ H,
                                            float* __restrict__ O) {
    int wave = threadIdx.x >> 6;
    int lane = threadIdx.x & 63;
    int row = blockIdx.x * 4 + wave;
    if (row >= NN) return;
    int beg = row_ptr[row];
    int end = row_ptr[row + 1];
    const float4* __restrict__ H4 = reinterpret_cast<const float4*>(H);
    float4 acc = make_float4(0.f, 0.f, 0.f, 0.f);
    for (int e = beg; e < end; ++e) {
        int s = csr_src[e];
        float v = csr_val[e];
        float4 hv = H4[(size_t)s * 64 + lane];
        acc.x += v * hv.x;
        acc.y += v * hv.y;
        acc.z += v * hv.z;
        acc.w += v * hv.w;
    }
    reinterpret_cast<float4*>(O)[(size_t)row * 64 + lane] = acc;
}

// ---------------- fp32 tiled GEMM, C = A[M,256] @ B[256,N], optional ReLU ----------------

template <int RELU>
__global__ __launch_bounds__(256) void gemm_relu(const float* __restrict__ A, const float* __restrict__ B,
                                                 float* __restrict__ Cout, int M, int N) {
    const int K = FD;
    __shared__ float As[16][65];
    __shared__ float Bs[16][65];
    int bm = blockIdx.x * 64;
    int bn = blockIdx.y * 64;
    int tid = threadIdx.x;
    int tr = (tid / 16) * 4;
    int tc = (tid % 16) * 4;
    float acc[4][4] = {};

    for (int k0 = 0; k0 < K; k0 += 16) {
        // A tile: 64 rows x 16 k; one float4 per thread
        int ar = tid >> 2;
        int akq = (tid & 3) * 4;
        float4 av = make_float4(0.f, 0.f, 0.f, 0.f);
        if (bm + ar < M) av = *reinterpret_cast<const float4*>(&A[(size_t)(bm + ar) * K + k0 + akq]);
        As[akq + 0][ar] = av.x;
        As[akq + 1][ar] = av.y;
        As[akq + 2][ar] = av.z;
        As[akq + 3][ar] = av.w;
        // B tile: 16 k x 64 cols; one float4 per thread
        int br = tid >> 4;
        int bc = (tid & 15) * 4;
        float4 bv;
        if (bn + bc + 3 < N) {
            bv = *reinterpret_cast<const float4*>(&B[(size_t)(k0 + br) * N + bn + bc]);
        } else {
            float tmp[4] = {0.f, 0.f, 0.f, 0.f};
            for (int j = 0; j < 4; ++j)
                if (bn + bc + j < N) tmp[j] = B[(size_t)(k0 + br) * N + bn + bc + j];
            bv = make_float4(tmp[0], tmp[1], tmp[2], tmp[3]);
        }
        Bs[br][bc + 0] = bv.x;
        Bs[br][bc + 1] = bv.y;
        Bs[br][bc + 2] = bv.z;
        Bs[br][bc + 3] = bv.w;
        __syncthreads();
#pragma unroll
        for (int kk = 0; kk < 16; ++kk) {
            float a[4], b[4];
#pragma unroll
            for (int i = 0; i < 4; ++i) a[i] = As[kk][tr + i];
#pragma unroll
            for (int j = 0; j < 4; ++j) b[j] = Bs[kk][tc + j];
#pragma unroll
            for (int i = 0; i < 4; ++i)
#pragma unroll
                for (int j = 0; j < 4; ++j) acc[i][j] += a[i] * b[j];
        }
        __syncthreads();
    }

#pragma unroll
    for (int i = 0; i < 4; ++i) {
        int r = bm + tr + i;
        if (r >= M) continue;
#pragma unroll
        for (int j = 0; j < 4; ++j) {
            int c = bn + tc + j;
            if (c >= N) continue;
            float v = acc[i][j];
            if (RELU) v = fmaxf(v, 0.f);
            Cout[(size_t)r * N + c] = v;
        }
    }
}

// ---------------- log_softmax over 40 classes, one wave per row, in place ----------------

__global__ __launch_bounds__(256) void log_softmax40(float* __restrict__ out) {
    int wave = threadIdx.x >> 6;
    int lane = threadIdx.x & 63;
    int row = blockIdx.x * 4 + wave;
    if (row >= NN) return;
    float v = (lane < NC) ? out[(size_t)row * NC + lane] : -INFINITY;
    float m = v;
    for (int d = 32; d > 0; d >>= 1) m = fmaxf(m, __shfl_xor(m, d));
    float e = (lane < NC) ? expf(v - m) : 0.f;
    float ssum = e;
    for (int d = 32; d > 0; d >>= 1) ssum += __shfl_xor(ssum, d);
    float ls = logf(ssum);
    if (lane < NC) out[(size_t)row * NC + lane] = v - m - ls;
}

// ---------------- launch ----------------

extern "C" void kernel_launch(void* const* d_in, const int* in_sizes, int n_in,
                              void* d_out, int out_size, void* d_ws, size_t ws_size,
                              hipStream_t stream) {
    const float* x  = (const float*)d_in[0];
    const int*   ei = (const int*)d_in[1];
    const float* ev = (const float*)d_in[2];
    const float* W1 = (const float*)d_in[3];
    const float* W2 = (const float*)d_in[4];
    const float* W3 = (const float*)d_in[5];
    float* out = (float*)d_out;

    char* ws = (char*)d_ws;
    const size_t FEAT_BYTES = (size_t)NN * FD * sizeof(float);   // 102,400,000
    float* bufA    = (float*)(ws);
    float* bufB    = (float*)(ws + FEAT_BYTES);
    int*   csr_src = (int*)  (ws + 2 * FEAT_BYTES);
    float* csr_val = (float*)(ws + 2 * FEAT_BYTES + (size_t)NE * 4);
    int*   row_ptr = (int*)  (ws + 2 * FEAT_BYTES + (size_t)NE * 8);
    int*   wptr    = (int*)  (ws + 2 * FEAT_BYTES + (size_t)NE * 8 + 400128);
    int*   chunks  = (int*)  (ws + 2 * FEAT_BYTES + (size_t)NE * 8 + 2 * 400128);

    const int NCHUNK = (NN + 255) / 256;        // 391
    const int EGRID  = (NE + 255) / 256;        // 12500
    const int RGRID  = (NN + 3) / 4;            // 25000
    const int MGRID  = (NN + 63) / 64;          // 1563

    // CSR build (counts live in wptr)
    hipMemsetAsync(wptr, 0, (size_t)NN * sizeof(int), stream);
    edge_hist<<<EGRID, 256, 0, stream>>>(ei, wptr);
    chunk_sum<<<NCHUNK, 256, 0, stream>>>(wptr, chunks);
    scan_chunks<<<1, 512, 0, stream>>>(chunks, NCHUNK, row_ptr);
    block_scan<<<NCHUNK, 256, 0, stream>>>(wptr, chunks, row_ptr);
    edge_scatter<<<EGRID, 256, 0, stream>>>(ei, ev, wptr, csr_src, csr_val);

    // Layer 1: A@x -> bufA ; bufA@W1 relu -> bufB
    spmm<<<RGRID, 256, 0, stream>>>(row_ptr, csr_src, csr_val, x, bufA);
    gemm_relu<1><<<dim3(MGRID, 4), 256, 0, stream>>>(bufA, W1, bufB, NN, FD);

    // Layer 2
    spmm<<<RGRID, 256, 0, stream>>>(row_ptr, csr_src, csr_val, bufB, bufA);
    gemm_relu<1><<<dim3(MGRID, 4), 256, 0, stream>>>(bufA, W2, bufB, NN, FD);

    // Layer 3: spmm -> bufA ; bufA@W3 -> d_out (logits) ; log_softmax in place
    spmm<<<RGRID, 256, 0, stream>>>(row_ptr, csr_src, csr_val, bufB, bufA);
    gemm_relu<0><<<dim3(MGRID, 1), 256, 0, stream>>>(bufA, W3, out, NN, NC);
    log_softmax40<<<RGRID, 256, 0, stream>>>(out);
}

// Round 2
// 1384.830 us; speedup vs baseline: 1.6729x; 1.6729x over previous
//
#include <hip/hip_runtime.h>
#include <math.h>

#define NN 100000
#define NE 3200000
#define FD 256        // feature dim
#define NC 40         // classes

typedef unsigned int u32;
typedef unsigned short ushort_t;
typedef __attribute__((ext_vector_type(8))) short short8;
typedef __attribute__((ext_vector_type(4))) float f32x4;

#define AS1 __attribute__((address_space(1)))
#define AS3 __attribute__((address_space(3)))

static __device__ __forceinline__ float bf2f(unsigned short h) {
    return __builtin_bit_cast(float, ((u32)h) << 16);
}
static __device__ __forceinline__ unsigned short f2bf(float f) {
    u32 u = __builtin_bit_cast(u32, f);
    u += 0x7fffu + ((u >> 16) & 1u);   // RNE
    return (unsigned short)(u >> 16);
}

// ---------------- CSR build ----------------

__global__ __launch_bounds__(256) void edge_hist(const int* __restrict__ ei, int* __restrict__ counts) {
    int i = blockIdx.x * 256 + threadIdx.x;
    if (i < NE) atomicAdd(&counts[ei[NE + i]], 1);
}

__global__ __launch_bounds__(256) void chunk_sum(const int* __restrict__ counts, int* __restrict__ chunk_sums) {
    __shared__ int sh[256];
    int t = threadIdx.x;
    int i = blockIdx.x * 256 + t;
    sh[t] = (i < NN) ? counts[i] : 0;
    __syncthreads();
    for (int d = 128; d > 0; d >>= 1) {
        if (t < d) sh[t] += sh[t + d];
        __syncthreads();
    }
    if (t == 0) chunk_sums[blockIdx.x] = sh[0];
}

__global__ __launch_bounds__(512) void scan_chunks(int* __restrict__ chunk_sums, int nchunk, int* __restrict__ row_ptr) {
    __shared__ int s[512];
    int t = threadIdx.x;
    int v = (t < nchunk) ? chunk_sums[t] : 0;
    s[t] = v;
    __syncthreads();
    for (int d = 1; d < 512; d <<= 1) {
        int x = (t >= d) ? s[t - d] : 0;
        __syncthreads();
        s[t] += x;
        __syncthreads();
    }
    if (t < nchunk) chunk_sums[t] = s[t] - v;
    if (t == 0) row_ptr[NN] = NE;
}

__global__ __launch_bounds__(256) void block_scan(int* __restrict__ wptr, const int* __restrict__ chunk_sums,
                                                  int* __restrict__ row_ptr) {
    __shared__ int s[256];
    int t = threadIdx.x;
    int i = blockIdx.x * 256 + t;
    int v = (i < NN) ? wptr[i] : 0;
    s[t] = v;
    __syncthreads();
    for (int d = 1; d < 256; d <<= 1) {
        int x = (t >= d) ? s[t - d] : 0;
        __syncthreads();
        s[t] += x;
        __syncthreads();
    }
    int excl = s[t] - v + chunk_sums[blockIdx.x];
    if (i < NN) {
        row_ptr[i] = excl;
        wptr[i] = excl;
    }
}

__global__ __launch_bounds__(256) void edge_scatter(const int* __restrict__ ei, const float* __restrict__ ev,
                                                    int* __restrict__ wptr,
                                                    int* __restrict__ csr_src, float* __restrict__ csr_val) {
    int i = blockIdx.x * 256 + threadIdx.x;
    if (i < NE) {
        int s = ei[i];
        int d = ei[NE + i];
        int p = atomicAdd(&wptr[d], 1);
        csr_src[p] = s;
        csr_val[p] = ev[i];
    }
}

// ---------------- conversions ----------------

__global__ __launch_bounds__(256) void f2bf_vec(const float* __restrict__ X, unsigned short* __restrict__ Y, int n4) {
    int i = blockIdx.x * 256 + threadIdx.x;
    if (i < n4) {
        float4 v = reinterpret_cast<const float4*>(X)[i];
        ushort4 o;
        o.x = f2bf(v.x); o.y = f2bf(v.y); o.z = f2bf(v.z); o.w = f2bf(v.w);
        reinterpret_cast<ushort4*>(Y)[i] = o;
    }
}

// Wt[n][k] = bf16(W[k][n]) for 256x256 W
__global__ __launch_bounds__(256) void transpose_w(const float* __restrict__ W, unsigned short* __restrict__ Wt) {
    int n = blockIdx.x, k = threadIdx.x;
    Wt[n * 256 + k] = f2bf(W[k * 256 + n]);
}

// Wt3p[n][k] = bf16(W3[k][n]) for n<40, else 0 (48 padded rows)
__global__ __launch_bounds__(256) void build_wt3(const float* __restrict__ W3, unsigned short* __restrict__ Wt3p) {
    int n = blockIdx.x, k = threadIdx.x;
    Wt3p[n * 256 + k] = (n < NC) ? f2bf(W3[k * NC + n]) : 0;
}

// ---------------- SPMM bf16: one wave per dst row, 4 bf16 per lane ----------------

__global__ __launch_bounds__(256) void spmm_bf16(const int* __restrict__ rp,
                                                 const int* __restrict__ csrc,
                                                 const float* __restrict__ cval,
                                                 const unsigned short* __restrict__ H,
                                                 unsigned short* __restrict__ O) {
    int wv = threadIdx.x >> 6;
    int l = threadIdx.x & 63;
    int row = blockIdx.x * 4 + wv;
    if (row >= NN) return;
    int beg = rp[row];
    int end = rp[row + 1];
    const ushort4* __restrict__ H4 = reinterpret_cast<const ushort4*>(H);
    float a0 = 0.f, a1 = 0.f, a2 = 0.f, a3 = 0.f;
    for (int e = beg; e < end; ++e) {
        int s = csrc[e];
        float v = cval[e];
        ushort4 hv = H4[(size_t)s * 64 + l];
        a0 += v * bf2f(hv.x);
        a1 += v * bf2f(hv.y);
        a2 += v * bf2f(hv.z);
        a3 += v * bf2f(hv.w);
    }
    ushort4 o;
    o.x = f2bf(a0); o.y = f2bf(a1); o.z = f2bf(a2); o.w = f2bf(a3);
    reinterpret_cast<ushort4*>(O)[(size_t)row * 64 + l] = o;
}

// ---------------- MFMA GEMM: C[M,256] = A[M,256](bf16) @ W(bf16, Wt[n][k]), opt ReLU, out bf16 ----

#define BM 128
#define BKK 64

__global__ __launch_bounds__(256) void gemm_mfma(const unsigned short* __restrict__ A,
                                                 const unsigned short* __restrict__ Wt,
                                                 unsigned short* __restrict__ C, int M, int relu) {
    __shared__ unsigned short As[BM * BKK];
    __shared__ unsigned short Bs[BM * BKK];
    int tid = threadIdx.x;
    int l = tid & 63;
    int w = tid >> 6;
    int wm = w >> 1, wn = w & 1;
    int bm = blockIdx.x * BM;
    int bn = blockIdx.y * BM;

    f32x4 acc[4][4] = {};

    for (int kt = 0; kt < 4; ++kt) {
        int k0 = kt * BKK;
#pragma unroll
        for (int i = 0; i < 4; ++i) {
            int e = i * 256 + tid;
            int row = e >> 3;          // 0..127
            int c = e & 7;             // 16B chunk within 128B row
            int cs = c ^ (row & 7);    // inverse-swizzled global source
            int ga = min(bm + row, M - 1);
            __builtin_amdgcn_global_load_lds(
                (const AS1 u32*)(A + (size_t)ga * 256 + k0 + cs * 8),
                (AS3 u32*)(As + e * 8), 16, 0, 0);
            __builtin_amdgcn_global_load_lds(
                (const AS1 u32*)(Wt + (size_t)(bn + row) * 256 + k0 + cs * 8),
                (AS3 u32*)(Bs + e * 8), 16, 0, 0);
        }
        __syncthreads();
#pragma unroll
        for (int h = 0; h < 2; ++h) {
            short8 av[4], bv[4];
#pragma unroll
            for (int m = 0; m < 4; ++m) {
                int row = wm * 64 + m * 16 + (l & 15);
                int cs = (h * 4 + (l >> 4)) ^ (row & 7);
                av[m] = *(const short8*)(As + row * BKK + cs * 8);
            }
#pragma unroll
            for (int n = 0; n < 4; ++n) {
                int row = wn * 64 + n * 16 + (l & 15);
                int cs = (h * 4 + (l >> 4)) ^ (row & 7);
                bv[n] = *(const short8*)(Bs + row * BKK + cs * 8);
            }
#pragma unroll
            for (int m = 0; m < 4; ++m)
#pragma unroll
                for (int n = 0; n < 4; ++n)
                    acc[m][n] = __builtin_amdgcn_mfma_f32_16x16x32_bf16(av[m], bv[n], acc[m][n], 0, 0, 0);
        }
        __syncthreads();
    }

#pragma unroll
    for (int m = 0; m < 4; ++m)
#pragma unroll
        for (int r = 0; r < 4; ++r) {
            int gr = bm + wm * 64 + m * 16 + (l >> 4) * 4 + r;
            if (gr >= M) continue;
#pragma unroll
            for (int n = 0; n < 4; ++n) {
                int gc = bn + wn * 64 + n * 16 + (l & 15);
                float v = acc[m][n][r];
                if (relu) v = fmaxf(v, 0.f);
                C[(size_t)gr * 256 + gc] = f2bf(v);
            }
        }
}

// ---------------- GEMM3: logits[M,40] = H2[M,256](bf16) @ W3 (Wt3p[48][256] bf16), fp32 out ----

__global__ __launch_bounds__(256) void gemm3_mfma(const unsigned short* __restrict__ H2,
                                                  const unsigned short* __restrict__ Wt3p,
                                                  float* __restrict__ L) {
    int tid = threadIdx.x, l = tid & 63, w = tid >> 6;
    int row0 = blockIdx.x * 64 + w * 16;
    f32x4 acc[3] = {};
    int ra = min(row0 + (l & 15), NN - 1);
    const unsigned short* ap = H2 + (size_t)ra * 256 + (l >> 4) * 8;
#pragma unroll
    for (int kt = 0; kt < 8; ++kt) {
        short8 av = *(const short8*)(ap + kt * 32);
#pragma unroll
        for (int j = 0; j < 3; ++j) {
            const unsigned short* bp = Wt3p + (size_t)(j * 16 + (l & 15)) * 256 + kt * 32 + (l >> 4) * 8;
            short8 bv = *(const short8*)bp;
            acc[j] = __builtin_amdgcn_mfma_f32_16x16x32_bf16(av, bv, acc[j], 0, 0, 0);
        }
    }
#pragma unroll
    for (int j = 0; j < 3; ++j)
#pragma unroll
        for (int r = 0; r < 4; ++r) {
            int gr = row0 + (l >> 4) * 4 + r;
            int gc = j * 16 + (l & 15);
            if (gr < NN && gc < NC) L[(size_t)gr * NC + gc] = acc[j][r];
        }
}

// ---------------- SPMM on 40-wide fp32 logits ----------------

__global__ __launch_bounds__(256) void spmm40(const int* __restrict__ rp, const int* __restrict__ csrc,
                                              const float* __restrict__ cval,
                                              const float* __restrict__ L, float* __restrict__ O) {
    int wv = threadIdx.x >> 6, l = threadIdx.x & 63;
    int row = blockIdx.x * 4 + wv;
    if (row >= NN) return;
    int beg = rp[row], end = rp[row + 1];
    int lc = min(l, NC - 1);
    float acc = 0.f;
    for (int e = beg; e < end; ++e) {
        int s = csrc[e];
        float v = cval[e];
        acc += v * L[(size_t)s * NC + lc];
    }
    if (l < NC) O[(size_t)row * NC + l] = acc;
}

// ---------------- log_softmax over 40 classes ----------------

__global__ __launch_bounds__(256) void log_softmax40(float* __restrict__ out) {
    int wv = threadIdx.x >> 6;
    int l = threadIdx.x & 63;
    int row = blockIdx.x * 4 + wv;
    if (row >= NN) return;
    float v = (l < NC) ? out[(size_t)row * NC + l] : -INFINITY;
    float m = v;
    for (int d = 32; d > 0; d >>= 1) m = fmaxf(m, __shfl_xor(m, d));
    float e = (l < NC) ? expf(v - m) : 0.f;
    float ssum = e;
    for (int d = 32; d > 0; d >>= 1) ssum += __shfl_xor(ssum, d);
    float ls = logf(ssum);
    if (l < NC) out[(size_t)row * NC + l] = v - m - ls;
}

// ---------------- launch ----------------

extern "C" void kernel_launch(void* const* d_in, const int* in_sizes, int n_in,
                              void* d_out, int out_size, void* d_ws, size_t ws_size,
                              hipStream_t stream) {
    const float* x  = (const float*)d_in[0];
    const int*   ei = (const int*)d_in[1];
    const float* ev = (const float*)d_in[2];
    const float* W1 = (const float*)d_in[3];
    const float* W2 = (const float*)d_in[4];
    const float* W3 = (const float*)d_in[5];
    float* out = (float*)d_out;

    char* ws = (char*)d_ws;
    size_t o = 0;
    unsigned short* B0 = (unsigned short*)(ws + o); o += (size_t)NN * FD * 2;   // 51.2 MB
    unsigned short* B1 = (unsigned short*)(ws + o); o += (size_t)NN * FD * 2;   // 51.2 MB
    float* logits      = (float*)(ws + o);          o += (size_t)NN * NC * 4;   // 16 MB
    int*   csr_src     = (int*)(ws + o);            o += (size_t)NE * 4;
    float* csr_val     = (float*)(ws + o);          o += (size_t)NE * 4;
    int*   row_ptr     = (int*)(ws + o);            o += 400128;
    int*   wptr        = (int*)(ws + o);            o += 400128;
    int*   chunks      = (int*)(ws + o);            o += 2048;
    unsigned short* Wt1  = (unsigned short*)(ws + o); o += 256 * 256 * 2;
    unsigned short* Wt2  = (unsigned short*)(ws + o); o += 256 * 256 * 2;
    unsigned short* Wt3p = (unsigned short*)(ws + o); o += 48 * 256 * 2;

    const int NCHUNK = (NN + 255) / 256;        // 391
    const int EGRID  = (NE + 255) / 256;        // 12500
    const int RGRID  = (NN + 3) / 4;            // 25000
    const int CGRID  = (NN * FD / 4 + 255) / 256; // 25000
    const int GXM    = (NN + BM - 1) / BM;      // 782
    const int G3     = (NN + 63) / 64;          // 1563

    // CSR build (counts live in wptr)
    hipMemsetAsync(wptr, 0, (size_t)NN * sizeof(int), stream);
    edge_hist<<<EGRID, 256, 0, stream>>>(ei, wptr);
    chunk_sum<<<NCHUNK, 256, 0, stream>>>(wptr, chunks);
    scan_chunks<<<1, 512, 0, stream>>>(chunks, NCHUNK, row_ptr);
    block_scan<<<NCHUNK, 256, 0, stream>>>(wptr, chunks, row_ptr);
    edge_scatter<<<EGRID, 256, 0, stream>>>(ei, ev, wptr, csr_src, csr_val);

    // conversions
    f2bf_vec<<<CGRID, 256, 0, stream>>>(x, B0, NN * FD / 4);
    transpose_w<<<256, 256, 0, stream>>>(W1, Wt1);
    transpose_w<<<256, 256, 0, stream>>>(W2, Wt2);
    build_wt3<<<48, 256, 0, stream>>>(W3, Wt3p);

    // Layer 1: spmm(x) @ W1, relu
    spmm_bf16<<<RGRID, 256, 0, stream>>>(row_ptr, csr_src, csr_val, B0, B1);
    gemm_mfma<<<dim3(GXM, 2), 256, 0, stream>>>(B1, Wt1, B0, NN, 1);

    // Layer 2
    spmm_bf16<<<RGRID, 256, 0, stream>>>(row_ptr, csr_src, csr_val, B0, B1);
    gemm_mfma<<<dim3(GXM, 2), 256, 0, stream>>>(B1, Wt2, B0, NN, 1);

    // Layer 3 (reordered): logits = H2 @ W3, then spmm on 40-wide, then log_softmax
    gemm3_mfma<<<G3, 256, 0, stream>>>(B0, Wt3p, logits);
    spmm40<<<RGRID, 256, 0, stream>>>(row_ptr, csr_src, csr_val, logits, out);
    log_softmax40<<<RGRID, 256, 0, stream>>>(out);
}

// Round 3
// 988.522 us; speedup vs baseline: 2.3436x; 1.4009x over previous
//
#include <hip/hip_runtime.h>
#include <math.h>

#define NN 100000
#define NE 3200000
#define FD 256        // feature dim
#define NC 40         // classes

typedef unsigned int u32;
typedef __attribute__((ext_vector_type(8))) short short8;
typedef __attribute__((ext_vector_type(4))) float f32x4;

#define AS1 __attribute__((address_space(1)))
#define AS3 __attribute__((address_space(3)))

static __device__ __forceinline__ float bf2f(unsigned short h) {
    return __builtin_bit_cast(float, ((u32)h) << 16);
}
static __device__ __forceinline__ unsigned short f2bf(float f) {
    u32 u = __builtin_bit_cast(u32, f);
    u += 0x7fffu + ((u >> 16) & 1u);   // RNE
    return (unsigned short)(u >> 16);
}

// ---------------- CSR build ----------------

__global__ __launch_bounds__(256) void edge_hist(const int* __restrict__ ei, int* __restrict__ counts) {
    int i = blockIdx.x * 256 + threadIdx.x;
    if (i < NE) atomicAdd(&counts[ei[NE + i]], 1);
}

__global__ __launch_bounds__(256) void chunk_sum(const int* __restrict__ counts, int* __restrict__ chunk_sums) {
    __shared__ int sh[256];
    int t = threadIdx.x;
    int i = blockIdx.x * 256 + t;
    sh[t] = (i < NN) ? counts[i] : 0;
    __syncthreads();
    for (int d = 128; d > 0; d >>= 1) {
        if (t < d) sh[t] += sh[t + d];
        __syncthreads();
    }
    if (t == 0) chunk_sums[blockIdx.x] = sh[0];
}

__global__ __launch_bounds__(512) void scan_chunks(int* __restrict__ chunk_sums, int nchunk, int* __restrict__ row_ptr) {
    __shared__ int s[512];
    int t = threadIdx.x;
    int v = (t < nchunk) ? chunk_sums[t] : 0;
    s[t] = v;
    __syncthreads();
    for (int d = 1; d < 512; d <<= 1) {
        int x = (t >= d) ? s[t - d] : 0;
        __syncthreads();
        s[t] += x;
        __syncthreads();
    }
    if (t < nchunk) chunk_sums[t] = s[t] - v;
    if (t == 0) row_ptr[NN] = NE;
}

__global__ __launch_bounds__(256) void block_scan(int* __restrict__ wptr, const int* __restrict__ chunk_sums,
                                                  int* __restrict__ row_ptr) {
    __shared__ int s[256];
    int t = threadIdx.x;
    int i = blockIdx.x * 256 + t;
    int v = (i < NN) ? wptr[i] : 0;
    s[t] = v;
    __syncthreads();
    for (int d = 1; d < 256; d <<= 1) {
        int x = (t >= d) ? s[t - d] : 0;
        __syncthreads();
        s[t] += x;
        __syncthreads();
    }
    int excl = s[t] - v + chunk_sums[blockIdx.x];
    if (i < NN) {
        row_ptr[i] = excl;
        wptr[i] = excl;
    }
}

__global__ __launch_bounds__(256) void edge_scatter(const int* __restrict__ ei, const float* __restrict__ ev,
                                                    int* __restrict__ wptr, int2* __restrict__ cp) {
    int i = blockIdx.x * 256 + threadIdx.x;
    if (i < NE) {
        int s = ei[i];
        int d = ei[NE + i];
        int p = atomicAdd(&wptr[d], 1);
        cp[p] = make_int2(s, __float_as_int(ev[i]));
    }
}

// ---------------- conversions ----------------

__global__ __launch_bounds__(256) void f2bf_vec(const float* __restrict__ X, unsigned short* __restrict__ Y, int n4) {
    int i = blockIdx.x * 256 + threadIdx.x;
    if (i < n4) {
        float4 v = reinterpret_cast<const float4*>(X)[i];
        ushort4 o;
        o.x = f2bf(v.x); o.y = f2bf(v.y); o.z = f2bf(v.z); o.w = f2bf(v.w);
        reinterpret_cast<ushort4*>(Y)[i] = o;
    }
}

__global__ __launch_bounds__(256) void transpose_w(const float* __restrict__ W, unsigned short* __restrict__ Wt) {
    int n = blockIdx.x, k = threadIdx.x;
    Wt[n * 256 + k] = f2bf(W[k * 256 + n]);
}

__global__ __launch_bounds__(256) void build_wt3(const float* __restrict__ W3, unsigned short* __restrict__ Wt3p) {
    int n = blockIdx.x, k = threadIdx.x;
    Wt3p[n * 256 + k] = (n < NC) ? f2bf(W3[k * NC + n]) : 0;
}

// ---------------- SPMM bf16: one wave per dst row, 8-deep pipelined gather ----------------

__global__ __launch_bounds__(256) void spmm_bf16(const int* __restrict__ rp,
                                                 const int2* __restrict__ cp,
                                                 const unsigned short* __restrict__ H,
                                                 unsigned short* __restrict__ O) {
    int wv = threadIdx.x >> 6;
    int l = threadIdx.x & 63;
    int row = blockIdx.x * 4 + wv;
    if (row >= NN) return;
    int beg = __builtin_amdgcn_readfirstlane(rp[row]);
    int end = __builtin_amdgcn_readfirstlane(rp[row + 1]);
    const ushort4* __restrict__ H4 = reinterpret_cast<const ushort4*>(H);
    float a0 = 0.f, a1 = 0.f, a2 = 0.f, a3 = 0.f;

    int e = beg;
    int efull = beg + ((end - beg) & ~7);
    if (e < efull) {
        int2 m[8];
#pragma unroll
        for (int j = 0; j < 8; ++j) m[j] = cp[e + j];
        e += 8;
        for (; e < efull; e += 8) {
            int2 mn[8];
#pragma unroll
            for (int j = 0; j < 8; ++j) mn[j] = cp[e + j];   // prefetch next chunk
#pragma unroll
            for (int j = 0; j < 8; ++j) {                    // 8 independent gathers
                ushort4 hv = H4[(size_t)m[j].x * 64 + l];
                float v = __int_as_float(m[j].y);
                a0 += v * bf2f(hv.x);
                a1 += v * bf2f(hv.y);
                a2 += v * bf2f(hv.z);
                a3 += v * bf2f(hv.w);
            }
#pragma unroll
            for (int j = 0; j < 8; ++j) m[j] = mn[j];
        }
#pragma unroll
        for (int j = 0; j < 8; ++j) {
            ushort4 hv = H4[(size_t)m[j].x * 64 + l];
            float v = __int_as_float(m[j].y);
            a0 += v * bf2f(hv.x);
            a1 += v * bf2f(hv.y);
            a2 += v * bf2f(hv.z);
            a3 += v * bf2f(hv.w);
        }
    }
    for (; e < end; ++e) {
        int2 m1 = cp[e];
        ushort4 hv = H4[(size_t)m1.x * 64 + l];
        float v = __int_as_float(m1.y);
        a0 += v * bf2f(hv.x);
        a1 += v * bf2f(hv.y);
        a2 += v * bf2f(hv.z);
        a3 += v * bf2f(hv.w);
    }
    ushort4 o;
    o.x = f2bf(a0); o.y = f2bf(a1); o.z = f2bf(a2); o.w = f2bf(a3);
    reinterpret_cast<ushort4*>(O)[(size_t)row * 64 + l] = o;
}

// ---------------- MFMA GEMM: C[M,256] = A[M,256](bf16) @ Wt[n][k](bf16), opt ReLU, out bf16 ----

#define BM 128
#define BKK 64

__global__ __launch_bounds__(256) void gemm_mfma(const unsigned short* __restrict__ A,
                                                 const unsigned short* __restrict__ Wt,
                                                 unsigned short* __restrict__ C, int M, int relu) {
    __shared__ unsigned short As[BM * BKK];
    __shared__ unsigned short Bs[BM * BKK];
    int tid = threadIdx.x;
    int l = tid & 63;
    int w = tid >> 6;
    int wm = w >> 1, wn = w & 1;
    int bm = blockIdx.x * BM;
    int bn = blockIdx.y * BM;

    f32x4 acc[4][4] = {};

    for (int kt = 0; kt < 4; ++kt) {
        int k0 = kt * BKK;
#pragma unroll
        for (int i = 0; i < 4; ++i) {
            int e = i * 256 + tid;
            int row = e >> 3;
            int c = e & 7;
            int cs = c ^ (row & 7);
            int ga = min(bm + row, M - 1);
            __builtin_amdgcn_global_load_lds(
                (const AS1 u32*)(A + (size_t)ga * 256 + k0 + cs * 8),
                (AS3 u32*)(As + e * 8), 16, 0, 0);
            __builtin_amdgcn_global_load_lds(
                (const AS1 u32*)(Wt + (size_t)(bn + row) * 256 + k0 + cs * 8),
                (AS3 u32*)(Bs + e * 8), 16, 0, 0);
        }
        __syncthreads();
#pragma unroll
        for (int h = 0; h < 2; ++h) {
            short8 av[4], bv[4];
#pragma unroll
            for (int m = 0; m < 4; ++m) {
                int row = wm * 64 + m * 16 + (l & 15);
                int cs = (h * 4 + (l >> 4)) ^ (row & 7);
                av[m] = *(const short8*)(As + row * BKK + cs * 8);
            }
#pragma unroll
            for (int n = 0; n < 4; ++n) {
                int row = wn * 64 + n * 16 + (l & 15);
                int cs = (h * 4 + (l >> 4)) ^ (row & 7);
                bv[n] = *(const short8*)(Bs + row * BKK + cs * 8);
            }
#pragma unroll
            for (int m = 0; m < 4; ++m)
#pragma unroll
                for (int n = 0; n < 4; ++n)
                    acc[m][n] = __builtin_amdgcn_mfma_f32_16x16x32_bf16(av[m], bv[n], acc[m][n], 0, 0, 0);
        }
        __syncthreads();
    }

#pragma unroll
    for (int m = 0; m < 4; ++m)
#pragma unroll
        for (int r = 0; r < 4; ++r) {
            int gr = bm + wm * 64 + m * 16 + (l >> 4) * 4 + r;
            if (gr >= M) continue;
#pragma unroll
            for (int n = 0; n < 4; ++n) {
                int gc = bn + wn * 64 + n * 16 + (l & 15);
                float v = acc[m][n][r];
                if (relu) v = fmaxf(v, 0.f);
                C[(size_t)gr * 256 + gc] = f2bf(v);
            }
        }
}

// ------- GEMM3: Lb[M,64](bf16, cols<48 valid) = H2[M,256](bf16) @ Wt3p[48][256](bf16) -------

__global__ __launch_bounds__(256) void gemm3_mfma(const unsigned short* __restrict__ H2,
                                                  const unsigned short* __restrict__ Wt3p,
                                                  unsigned short* __restrict__ Lb) {
    int tid = threadIdx.x, l = tid & 63, w = tid >> 6;
    int row0 = blockIdx.x * 64 + w * 16;
    f32x4 acc[3] = {};
    int ra = min(row0 + (l & 15), NN - 1);
    const unsigned short* ap = H2 + (size_t)ra * 256 + (l >> 4) * 8;
#pragma unroll
    for (int kt = 0; kt < 8; ++kt) {
        short8 av = *(const short8*)(ap + kt * 32);
#pragma unroll
        for (int j = 0; j < 3; ++j) {
            const unsigned short* bp = Wt3p + (size_t)(j * 16 + (l & 15)) * 256 + kt * 32 + (l >> 4) * 8;
            short8 bv = *(const short8*)bp;
            acc[j] = __builtin_amdgcn_mfma_f32_16x16x32_bf16(av, bv, acc[j], 0, 0, 0);
        }
    }
#pragma unroll
    for (int j = 0; j < 3; ++j)
#pragma unroll
        for (int r = 0; r < 4; ++r) {
            int gr = row0 + (l >> 4) * 4 + r;
            int gc = j * 16 + (l & 15);
            if (gr < NN) Lb[(size_t)gr * 64 + gc] = f2bf(acc[j][r]);
        }
}

// ------- fused: out[row] = log_softmax( sum_e val * Lb[src] ), wave per row -------

__global__ __launch_bounds__(256) void spmm40_lsm(const int* __restrict__ rp,
                                                  const int2* __restrict__ cp,
                                                  const unsigned short* __restrict__ Lb,
                                                  float* __restrict__ out) {
    int wv = threadIdx.x >> 6, l = threadIdx.x & 63;
    int row = blockIdx.x * 4 + wv;
    if (row >= NN) return;
    int beg = __builtin_amdgcn_readfirstlane(rp[row]);
    int end = __builtin_amdgcn_readfirstlane(rp[row + 1]);
    float acc = 0.f;
    int e = beg;
    int efull = beg + ((end - beg) & ~7);
    if (e < efull) {
        int2 m[8];
#pragma unroll
        for (int j = 0; j < 8; ++j) m[j] = cp[e + j];
        e += 8;
        for (; e < efull; e += 8) {
            int2 mn[8];
#pragma unroll
            for (int j = 0; j < 8; ++j) mn[j] = cp[e + j];
#pragma unroll
            for (int j = 0; j < 8; ++j)
                acc += __int_as_float(m[j].y) * bf2f(Lb[(size_t)m[j].x * 64 + l]);
#pragma unroll
            for (int j = 0; j < 8; ++j) m[j] = mn[j];
        }
#pragma unroll
        for (int j = 0; j < 8; ++j)
            acc += __int_as_float(m[j].y) * bf2f(Lb[(size_t)m[j].x * 64 + l]);
    }
    for (; e < end; ++e) {
        int2 m1 = cp[e];
        acc += __int_as_float(m1.y) * bf2f(Lb[(size_t)m1.x * 64 + l]);
    }
    // log_softmax over lanes 0..39
    float v = (l < NC) ? acc : -INFINITY;
    float mx = v;
    for (int d = 32; d > 0; d >>= 1) mx = fmaxf(mx, __shfl_xor(mx, d));
    float ex = (l < NC) ? expf(v - mx) : 0.f;
    float ssum = ex;
    for (int d = 32; d > 0; d >>= 1) ssum += __shfl_xor(ssum, d);
    float ls = logf(ssum);
    if (l < NC) out[(size_t)row * NC + l] = v - mx - ls;
}

// ---------------- launch ----------------

extern "C" void kernel_launch(void* const* d_in, const int* in_sizes, int n_in,
                              void* d_out, int out_size, void* d_ws, size_t ws_size,
                              hipStream_t stream) {
    const float* x  = (const float*)d_in[0];
    const int*   ei = (const int*)d_in[1];
    const float* ev = (const float*)d_in[2];
    const float* W1 = (const float*)d_in[3];
    const float* W2 = (const float*)d_in[4];
    const float* W3 = (const float*)d_in[5];
    float* out = (float*)d_out;

    char* ws = (char*)d_ws;
    size_t o = 0;
    unsigned short* B0 = (unsigned short*)(ws + o); o += (size_t)NN * FD * 2;   // 51.2 MB
    unsigned short* B1 = (unsigned short*)(ws + o); o += (size_t)NN * FD * 2;   // 51.2 MB
    unsigned short* Lb = (unsigned short*)(ws + o); o += (size_t)NN * 64 * 2;   // 12.8 MB
    int2*  cp          = (int2*)(ws + o);           o += (size_t)NE * 8;        // 25.6 MB
    int*   row_ptr     = (int*)(ws + o);            o += 400128;
    int*   wptr        = (int*)(ws + o);            o += 400128;
    int*   chunks      = (int*)(ws + o);            o += 2048;
    unsigned short* Wt1  = (unsigned short*)(ws + o); o += 256 * 256 * 2;
    unsigned short* Wt2  = (unsigned short*)(ws + o); o += 256 * 256 * 2;
    unsigned short* Wt3p = (unsigned short*)(ws + o); o += 48 * 256 * 2;

    const int NCHUNK = (NN + 255) / 256;          // 391
    const int EGRID  = (NE + 255) / 256;          // 12500
    const int RGRID  = (NN + 3) / 4;              // 25000
    const int CGRID  = (NN * FD / 4 + 255) / 256; // 25000
    const int GXM    = (NN + BM - 1) / BM;        // 782
    const int G3     = (NN + 63) / 64;            // 1563

    // CSR build (counts live in wptr)
    hipMemsetAsync(wptr, 0, (size_t)NN * sizeof(int), stream);
    edge_hist<<<EGRID, 256, 0, stream>>>(ei, wptr);
    chunk_sum<<<NCHUNK, 256, 0, stream>>>(wptr, chunks);
    scan_chunks<<<1, 512, 0, stream>>>(chunks, NCHUNK, row_ptr);
    block_scan<<<NCHUNK, 256, 0, stream>>>(wptr, chunks, row_ptr);
    edge_scatter<<<EGRID, 256, 0, stream>>>(ei, ev, wptr, cp);

    // conversions
    f2bf_vec<<<CGRID, 256, 0, stream>>>(x, B0, NN * FD / 4);
    transpose_w<<<256, 256, 0, stream>>>(W1, Wt1);
    transpose_w<<<256, 256, 0, stream>>>(W2, Wt2);
    build_wt3<<<48, 256, 0, stream>>>(W3, Wt3p);

    // Layer 1: spmm(x) @ W1, relu
    spmm_bf16<<<RGRID, 256, 0, stream>>>(row_ptr, cp, B0, B1);
    gemm_mfma<<<dim3(GXM, 2), 256, 0, stream>>>(B1, Wt1, B0, NN, 1);

    // Layer 2
    spmm_bf16<<<RGRID, 256, 0, stream>>>(row_ptr, cp, B0, B1);
    gemm_mfma<<<dim3(GXM, 2), 256, 0, stream>>>(B1, Wt2, B0, NN, 1);

    // Layer 3 (reordered): Lb = H2 @ W3 (bf16, padded 64), then fused spmm40 + log_softmax
    gemm3_mfma<<<G3, 256, 0, stream>>>(B0, Wt3p, Lb);
    spmm40_lsm<<<RGRID, 256, 0, stream>>>(row_ptr, cp, Lb, out);
}

// Round 4
// 808.642 us; speedup vs baseline: 2.8649x; 1.2224x over previous
//
#include <hip/hip_runtime.h>
#include <math.h>

#define NN 100000
#define NE 3200000
#define FD 256        // feature dim
#define NC 40         // classes
#define BN_BUCK 196   // ceil(NN / 512)

typedef unsigned int u32;
typedef __attribute__((ext_vector_type(8))) short short8;
typedef __attribute__((ext_vector_type(4))) float f32x4;

#define AS1 __attribute__((address_space(1)))
#define AS3 __attribute__((address_space(3)))

static __device__ __forceinline__ float bf2f(unsigned short h) {
    return __builtin_bit_cast(float, ((u32)h) << 16);
}
static __device__ __forceinline__ unsigned short f2bf(float f) {
    u32 u = __builtin_bit_cast(u32, f);
    u += 0x7fffu + ((u >> 16) & 1u);   // RNE
    return (unsigned short)(u >> 16);
}

// ---------------- binned CSR build ----------------
// bucket b = dst >> 9 (512 nodes per bucket, 196 buckets)

__global__ __launch_bounds__(256) void bucket_count(const int* __restrict__ ei_dst, int* __restrict__ gcount) {
    __shared__ int sh[BN_BUCK];
    int t = threadIdx.x;
    if (t < BN_BUCK) sh[t] = 0;
    __syncthreads();
    int i = blockIdx.x * 1024 + t * 4;
    int4 d = *reinterpret_cast<const int4*>(ei_dst + i);
    atomicAdd(&sh[d.x >> 9], 1);
    atomicAdd(&sh[d.y >> 9], 1);
    atomicAdd(&sh[d.z >> 9], 1);
    atomicAdd(&sh[d.w >> 9], 1);
    __syncthreads();
    if (t < BN_BUCK && sh[t]) atomicAdd(&gcount[t], sh[t]);
}

__global__ __launch_bounds__(256) void bucket_scan(const int* __restrict__ gcount,
                                                   int* __restrict__ bucketBase,
                                                   int* __restrict__ bucketFill,
                                                   int* __restrict__ row_ptr) {
    __shared__ int s[256];
    int t = threadIdx.x;
    int v = (t < BN_BUCK) ? gcount[t] : 0;
    s[t] = v;
    __syncthreads();
    for (int d = 1; d < 256; d <<= 1) {
        int x = (t >= d) ? s[t - d] : 0;
        __syncthreads();
        s[t] += x;
        __syncthreads();
    }
    int excl = s[t] - v;
    if (t < BN_BUCK) {
        bucketBase[t] = excl;
        bucketFill[t] = excl;
    }
    if (t == 0) {
        bucketBase[BN_BUCK] = NE;
        row_ptr[NN] = NE;
    }
}

// each block: 1024 edges -> grouped writes into per-bucket segments of ebuf (16B records)
__global__ __launch_bounds__(256) void partition_edges(const int* __restrict__ ei, const float* __restrict__ ev,
                                                       int* __restrict__ bucketFill, int4* __restrict__ ebuf) {
    __shared__ int cnt[BN_BUCK];
    __shared__ int gb[BN_BUCK];
    __shared__ int fill[BN_BUCK];
    int t = threadIdx.x;
    if (t < BN_BUCK) { cnt[t] = 0; fill[t] = 0; }
    __syncthreads();
    int i = blockIdx.x * 1024 + t * 4;
    int4 s4 = *reinterpret_cast<const int4*>(ei + i);
    int4 d4 = *reinterpret_cast<const int4*>(ei + NE + i);
    float4 v4 = *reinterpret_cast<const float4*>(ev + i);
    int b0 = d4.x >> 9, b1 = d4.y >> 9, b2 = d4.z >> 9, b3 = d4.w >> 9;
    atomicAdd(&cnt[b0], 1);
    atomicAdd(&cnt[b1], 1);
    atomicAdd(&cnt[b2], 1);
    atomicAdd(&cnt[b3], 1);
    __syncthreads();
    if (t < BN_BUCK && cnt[t]) gb[t] = atomicAdd(&bucketFill[t], cnt[t]);
    __syncthreads();
    int r;
    r = atomicAdd(&fill[b0], 1); ebuf[gb[b0] + r] = make_int4(d4.x, s4.x, __float_as_int(v4.x), 0);
    r = atomicAdd(&fill[b1], 1); ebuf[gb[b1] + r] = make_int4(d4.y, s4.y, __float_as_int(v4.y), 0);
    r = atomicAdd(&fill[b2], 1); ebuf[gb[b2] + r] = make_int4(d4.z, s4.z, __float_as_int(v4.z), 0);
    r = atomicAdd(&fill[b3], 1); ebuf[gb[b3] + r] = make_int4(d4.w, s4.w, __float_as_int(v4.w), 0);
}

// one workgroup per bucket: count 512 local nodes, scan -> row_ptr, place edges into cp
__global__ __launch_bounds__(256) void bucket_csr(const int* __restrict__ bucketBase,
                                                  const int4* __restrict__ ebuf,
                                                  int* __restrict__ row_ptr, int2* __restrict__ cp) {
    __shared__ int cnt[512];
    __shared__ int pairs[256];
    int b = blockIdx.x, t = threadIdx.x;
    int beg = bucketBase[b], end = bucketBase[b + 1];
    cnt[t] = 0;
    cnt[t + 256] = 0;
    __syncthreads();
    for (int e = beg + t; e < end; e += 256)
        atomicAdd(&cnt[ebuf[e].x & 511], 1);
    __syncthreads();
    int c0 = cnt[2 * t], c1 = cnt[2 * t + 1];
    int p = c0 + c1;
    pairs[t] = p;
    __syncthreads();
    for (int d = 1; d < 256; d <<= 1) {
        int x = (t >= d) ? pairs[t - d] : 0;
        __syncthreads();
        pairs[t] += x;
        __syncthreads();
    }
    int ep = pairs[t] - p;        // exclusive over node-pairs
    int e0 = ep, e1 = ep + c0;
    int g0 = b * 512 + 2 * t;
    if (g0 < NN) row_ptr[g0] = beg + e0;
    if (g0 + 1 < NN) row_ptr[g0 + 1] = beg + e1;
    __syncthreads();
    cnt[2 * t] = e0;              // reuse cnt as running fill offsets
    cnt[2 * t + 1] = e1;
    __syncthreads();
    for (int e = beg + t; e < end; e += 256) {
        int4 E = ebuf[e];
        int r = atomicAdd(&cnt[E.x & 511], 1);
        cp[beg + r] = make_int2(E.y, E.z);
    }
}

// ---------------- conversions ----------------

__global__ __launch_bounds__(256) void f2bf_vec(const float* __restrict__ X, unsigned short* __restrict__ Y, int n4) {
    int i = blockIdx.x * 256 + threadIdx.x;
    if (i < n4) {
        float4 v = reinterpret_cast<const float4*>(X)[i];
        ushort4 o;
        o.x = f2bf(v.x); o.y = f2bf(v.y); o.z = f2bf(v.z); o.w = f2bf(v.w);
        reinterpret_cast<ushort4*>(Y)[i] = o;
    }
}

__global__ __launch_bounds__(256) void transpose_w(const float* __restrict__ W, unsigned short* __restrict__ Wt) {
    int n = blockIdx.x, k = threadIdx.x;
    Wt[n * 256 + k] = f2bf(W[k * 256 + n]);
}

__global__ __launch_bounds__(256) void build_wt3(const float* __restrict__ W3, unsigned short* __restrict__ Wt3p) {
    int n = blockIdx.x, k = threadIdx.x;
    Wt3p[n * 256 + k] = (n < NC) ? f2bf(W3[k * NC + n]) : 0;
}

// ---------------- SPMM bf16: one wave per dst row, 8-deep pipelined gather ----------------

__global__ __launch_bounds__(256) void spmm_bf16(const int* __restrict__ rp,
                                                 const int2* __restrict__ cp,
                                                 const unsigned short* __restrict__ H,
                                                 unsigned short* __restrict__ O) {
    int wv = threadIdx.x >> 6;
    int l = threadIdx.x & 63;
    int row = blockIdx.x * 4 + wv;
    if (row >= NN) return;
    int beg = __builtin_amdgcn_readfirstlane(rp[row]);
    int end = __builtin_amdgcn_readfirstlane(rp[row + 1]);
    const ushort4* __restrict__ H4 = reinterpret_cast<const ushort4*>(H);
    float a0 = 0.f, a1 = 0.f, a2 = 0.f, a3 = 0.f;

    int e = beg;
    int efull = beg + ((end - beg) & ~7);
    if (e < efull) {
        int2 m[8];
#pragma unroll
        for (int j = 0; j < 8; ++j) m[j] = cp[e + j];
        e += 8;
        for (; e < efull; e += 8) {
            int2 mn[8];
#pragma unroll
            for (int j = 0; j < 8; ++j) mn[j] = cp[e + j];   // prefetch next chunk
#pragma unroll
            for (int j = 0; j < 8; ++j) {
                ushort4 hv = H4[(size_t)m[j].x * 64 + l];
                float v = __int_as_float(m[j].y);
                a0 += v * bf2f(hv.x);
                a1 += v * bf2f(hv.y);
                a2 += v * bf2f(hv.z);
                a3 += v * bf2f(hv.w);
            }
#pragma unroll
            for (int j = 0; j < 8; ++j) m[j] = mn[j];
        }
#pragma unroll
        for (int j = 0; j < 8; ++j) {
            ushort4 hv = H4[(size_t)m[j].x * 64 + l];
            float v = __int_as_float(m[j].y);
            a0 += v * bf2f(hv.x);
            a1 += v * bf2f(hv.y);
            a2 += v * bf2f(hv.z);
            a3 += v * bf2f(hv.w);
        }
    }
    for (; e < end; ++e) {
        int2 m1 = cp[e];
        ushort4 hv = H4[(size_t)m1.x * 64 + l];
        float v = __int_as_float(m1.y);
        a0 += v * bf2f(hv.x);
        a1 += v * bf2f(hv.y);
        a2 += v * bf2f(hv.z);
        a3 += v * bf2f(hv.w);
    }
    ushort4 o;
    o.x = f2bf(a0); o.y = f2bf(a1); o.z = f2bf(a2); o.w = f2bf(a3);
    reinterpret_cast<ushort4*>(O)[(size_t)row * 64 + l] = o;
}

// ---------------- MFMA GEMM: C[M,256] = A[M,256](bf16) @ Wt[n][k](bf16), opt ReLU, out bf16 ----

#define BM 128
#define BKK 64

__global__ __launch_bounds__(256) void gemm_mfma(const unsigned short* __restrict__ A,
                                                 const unsigned short* __restrict__ Wt,
                                                 unsigned short* __restrict__ C, int M, int relu) {
    __shared__ unsigned short As[BM * BKK];
    __shared__ unsigned short Bs[BM * BKK];
    int tid = threadIdx.x;
    int l = tid & 63;
    int w = tid >> 6;
    int wm = w >> 1, wn = w & 1;
    int bm = blockIdx.x * BM;
    int bn = blockIdx.y * BM;

    f32x4 acc[4][4] = {};

    for (int kt = 0; kt < 4; ++kt) {
        int k0 = kt * BKK;
#pragma unroll
        for (int i = 0; i < 4; ++i) {
            int e = i * 256 + tid;
            int row = e >> 3;
            int c = e & 7;
            int cs = c ^ (row & 7);
            int ga = min(bm + row, M - 1);
            __builtin_amdgcn_global_load_lds(
                (const AS1 u32*)(A + (size_t)ga * 256 + k0 + cs * 8),
                (AS3 u32*)(As + e * 8), 16, 0, 0);
            __builtin_amdgcn_global_load_lds(
                (const AS1 u32*)(Wt + (size_t)(bn + row) * 256 + k0 + cs * 8),
                (AS3 u32*)(Bs + e * 8), 16, 0, 0);
        }
        __syncthreads();
#pragma unroll
        for (int h = 0; h < 2; ++h) {
            short8 av[4], bv[4];
#pragma unroll
            for (int m = 0; m < 4; ++m) {
                int row = wm * 64 + m * 16 + (l & 15);
                int cs = (h * 4 + (l >> 4)) ^ (row & 7);
                av[m] = *(const short8*)(As + row * BKK + cs * 8);
            }
#pragma unroll
            for (int n = 0; n < 4; ++n) {
                int row = wn * 64 + n * 16 + (l & 15);
                int cs = (h * 4 + (l >> 4)) ^ (row & 7);
                bv[n] = *(const short8*)(Bs + row * BKK + cs * 8);
            }
#pragma unroll
            for (int m = 0; m < 4; ++m)
#pragma unroll
                for (int n = 0; n < 4; ++n)
                    acc[m][n] = __builtin_amdgcn_mfma_f32_16x16x32_bf16(av[m], bv[n], acc[m][n], 0, 0, 0);
        }
        __syncthreads();
    }

#pragma unroll
    for (int m = 0; m < 4; ++m)
#pragma unroll
        for (int r = 0; r < 4; ++r) {
            int gr = bm + wm * 64 + m * 16 + (l >> 4) * 4 + r;
            if (gr >= M) continue;
#pragma unroll
            for (int n = 0; n < 4; ++n) {
                int gc = bn + wn * 64 + n * 16 + (l & 15);
                float v = acc[m][n][r];
                if (relu) v = fmaxf(v, 0.f);
                C[(size_t)gr * 256 + gc] = f2bf(v);
            }
        }
}

// ------- GEMM3: Lb[M,64](bf16, cols<48 valid) = H2[M,256](bf16) @ Wt3p[48][256](bf16) -------

__global__ __launch_bounds__(256) void gemm3_mfma(const unsigned short* __restrict__ H2,
                                                  const unsigned short* __restrict__ Wt3p,
                                                  unsigned short* __restrict__ Lb) {
    int tid = threadIdx.x, l = tid & 63, w = tid >> 6;
    int row0 = blockIdx.x * 64 + w * 16;
    f32x4 acc[3] = {};
    int ra = min(row0 + (l & 15), NN - 1);
    const unsigned short* ap = H2 + (size_t)ra * 256 + (l >> 4) * 8;
#pragma unroll
    for (int kt = 0; kt < 8; ++kt) {
        short8 av = *(const short8*)(ap + kt * 32);
#pragma unroll
        for (int j = 0; j < 3; ++j) {
            const unsigned short* bp = Wt3p + (size_t)(j * 16 + (l & 15)) * 256 + kt * 32 + (l >> 4) * 8;
            short8 bv = *(const short8*)bp;
            acc[j] = __builtin_amdgcn_mfma_f32_16x16x32_bf16(av, bv, acc[j], 0, 0, 0);
        }
    }
#pragma unroll
    for (int j = 0; j < 3; ++j)
#pragma unroll
        for (int r = 0; r < 4; ++r) {
            int gr = row0 + (l >> 4) * 4 + r;
            int gc = j * 16 + (l & 15);
            if (gr < NN) Lb[(size_t)gr * 64 + gc] = f2bf(acc[j][r]);
        }
}

// ------- fused: out[row] = log_softmax( sum_e val * Lb[src] ), wave per row -------

__global__ __launch_bounds__(256) void spmm40_lsm(const int* __restrict__ rp,
                                                  const int2* __restrict__ cp,
                                                  const unsigned short* __restrict__ Lb,
                                                  float* __restrict__ out) {
    int wv = threadIdx.x >> 6, l = threadIdx.x & 63;
    int row = blockIdx.x * 4 + wv;
    if (row >= NN) return;
    int beg = __builtin_amdgcn_readfirstlane(rp[row]);
    int end = __builtin_amdgcn_readfirstlane(rp[row + 1]);
    float acc = 0.f;
    int e = beg;
    int efull = beg + ((end - beg) & ~7);
    if (e < efull) {
        int2 m[8];
#pragma unroll
        for (int j = 0; j < 8; ++j) m[j] = cp[e + j];
        e += 8;
        for (; e < efull; e += 8) {
            int2 mn[8];
#pragma unroll
            for (int j = 0; j < 8; ++j) mn[j] = cp[e + j];
#pragma unroll
            for (int j = 0; j < 8; ++j)
                acc += __int_as_float(m[j].y) * bf2f(Lb[(size_t)m[j].x * 64 + l]);
#pragma unroll
            for (int j = 0; j < 8; ++j) m[j] = mn[j];
        }
#pragma unroll
        for (int j = 0; j < 8; ++j)
            acc += __int_as_float(m[j].y) * bf2f(Lb[(size_t)m[j].x * 64 + l]);
    }
    for (; e < end; ++e) {
        int2 m1 = cp[e];
        acc += __int_as_float(m1.y) * bf2f(Lb[(size_t)m1.x * 64 + l]);
    }
    float v = (l < NC) ? acc : -INFINITY;
    float mx = v;
    for (int d = 32; d > 0; d >>= 1) mx = fmaxf(mx, __shfl_xor(mx, d));
    float ex = (l < NC) ? expf(v - mx) : 0.f;
    float ssum = ex;
    for (int d = 32; d > 0; d >>= 1) ssum += __shfl_xor(ssum, d);
    float ls = logf(ssum);
    if (l < NC) out[(size_t)row * NC + l] = v - mx - ls;
}

// ---------------- launch ----------------

extern "C" void kernel_launch(void* const* d_in, const int* in_sizes, int n_in,
                              void* d_out, int out_size, void* d_ws, size_t ws_size,
                              hipStream_t stream) {
    const float* x  = (const float*)d_in[0];
    const int*   ei = (const int*)d_in[1];
    const float* ev = (const float*)d_in[2];
    const float* W1 = (const float*)d_in[3];
    const float* W2 = (const float*)d_in[4];
    const float* W3 = (const float*)d_in[5];
    float* out = (float*)d_out;

    char* ws = (char*)d_ws;
    size_t o = 0;
    unsigned short* B0 = (unsigned short*)(ws + o); o += (size_t)NN * FD * 2;   // 51.2 MB
    unsigned short* B1 = (unsigned short*)(ws + o); o += (size_t)NN * FD * 2;   // 51.2 MB (aliases ebuf)
    unsigned short* Lb = (unsigned short*)(ws + o); o += (size_t)NN * 64 * 2;   // 12.8 MB
    int2*  cp          = (int2*)(ws + o);           o += (size_t)NE * 8;        // 25.6 MB
    int*   row_ptr     = (int*)(ws + o);            o += 400128;
    int*   gcount      = (int*)(ws + o);            o += 1024;
    int*   bucketBase  = (int*)(ws + o);            o += 1024;
    int*   bucketFill  = (int*)(ws + o);            o += 1024;
    unsigned short* Wt1  = (unsigned short*)(ws + o); o += 256 * 256 * 2;
    unsigned short* Wt2  = (unsigned short*)(ws + o); o += 256 * 256 * 2;
    unsigned short* Wt3p = (unsigned short*)(ws + o); o += 48 * 256 * 2;

    int4* ebuf = (int4*)B1;   // lifetime: partition_edges..bucket_csr, before B1's first write

    const int EB     = NE / 1024;                 // 3125 blocks for edge passes
    const int RGRID  = (NN + 3) / 4;              // 25000
    const int CGRID  = (NN * FD / 4 + 255) / 256; // 25000
    const int GXM    = (NN + BM - 1) / BM;        // 782
    const int G3     = (NN + 63) / 64;            // 1563

    // binned CSR build
    hipMemsetAsync(gcount, 0, BN_BUCK * sizeof(int), stream);
    bucket_count<<<EB, 256, 0, stream>>>(ei + NE, gcount);
    bucket_scan<<<1, 256, 0, stream>>>(gcount, bucketBase, bucketFill, row_ptr);
    partition_edges<<<EB, 256, 0, stream>>>(ei, ev, bucketFill, ebuf);
    bucket_csr<<<BN_BUCK, 256, 0, stream>>>(bucketBase, ebuf, row_ptr, cp);

    // conversions
    f2bf_vec<<<CGRID, 256, 0, stream>>>(x, B0, NN * FD / 4);
    transpose_w<<<256, 256, 0, stream>>>(W1, Wt1);
    transpose_w<<<256, 256, 0, stream>>>(W2, Wt2);
    build_wt3<<<48, 256, 0, stream>>>(W3, Wt3p);

    // Layer 1: spmm(x) @ W1, relu
    spmm_bf16<<<RGRID, 256, 0, stream>>>(row_ptr, cp, B0, B1);
    gemm_mfma<<<dim3(GXM, 2), 256, 0, stream>>>(B1, Wt1, B0, NN, 1);

    // Layer 2
    spmm_bf16<<<RGRID, 256, 0, stream>>>(row_ptr, cp, B0, B1);
    gemm_mfma<<<dim3(GXM, 2), 256, 0, stream>>>(B1, Wt2, B0, NN, 1);

    // Layer 3 (reordered): Lb = H2 @ W3 (bf16, padded 64), then fused spmm40 + log_softmax
    gemm3_mfma<<<G3, 256, 0, stream>>>(B0, Wt3p, Lb);
    spmm40_lsm<<<RGRID, 256, 0, stream>>>(row_ptr, cp, Lb, out);
}

// Round 5
// 792.701 us; speedup vs baseline: 2.9226x; 1.0201x over previous
//
#include <hip/hip_runtime.h>
#include <math.h>

#define NN 100000
#define NE 3200000
#define FD 256        // feature dim
#define NC 40         // classes
#define BN_BUCK 196   // ceil(NN / 512)

typedef unsigned int u32;
typedef __attribute__((ext_vector_type(8))) short short8;
typedef __attribute__((ext_vector_type(4))) float f32x4;

#define AS1 __attribute__((address_space(1)))
#define AS3 __attribute__((address_space(3)))

static __device__ __forceinline__ float bf2f(unsigned short h) {
    return __builtin_bit_cast(float, ((u32)h) << 16);
}
static __device__ __forceinline__ unsigned short f2bf(float f) {
    u32 u = __builtin_bit_cast(u32, f);
    u += 0x7fffu + ((u >> 16) & 1u);   // RNE
    return (unsigned short)(u >> 16);
}

// ---------------- binned CSR build ----------------
// bucket b = dst >> 9 (512 nodes per bucket, 196 buckets)
// ebuf record: int2{ (src<<9)|dst_local , val_bits }

__global__ __launch_bounds__(256) void bucket_count(const int* __restrict__ ei_dst, int* __restrict__ gcount) {
    __shared__ int sh[BN_BUCK];
    int t = threadIdx.x;
    if (t < BN_BUCK) sh[t] = 0;
    __syncthreads();
    int i = blockIdx.x * 1024 + t * 4;
    int4 d = *reinterpret_cast<const int4*>(ei_dst + i);
    atomicAdd(&sh[d.x >> 9], 1);
    atomicAdd(&sh[d.y >> 9], 1);
    atomicAdd(&sh[d.z >> 9], 1);
    atomicAdd(&sh[d.w >> 9], 1);
    __syncthreads();
    if (t < BN_BUCK && sh[t]) atomicAdd(&gcount[t], sh[t]);
}

__global__ __launch_bounds__(256) void bucket_scan(const int* __restrict__ gcount,
                                                   int* __restrict__ bucketBase,
                                                   int* __restrict__ bucketFill,
                                                   int* __restrict__ row_ptr) {
    __shared__ int s[256];
    int t = threadIdx.x;
    int v = (t < BN_BUCK) ? gcount[t] : 0;
    s[t] = v;
    __syncthreads();
    for (int d = 1; d < 256; d <<= 1) {
        int x = (t >= d) ? s[t - d] : 0;
        __syncthreads();
        s[t] += x;
        __syncthreads();
    }
    int excl = s[t] - v;
    if (t < BN_BUCK) {
        bucketBase[t] = excl;
        bucketFill[t] = excl;
    }
    if (t == 0) {
        bucketBase[BN_BUCK] = NE;
        row_ptr[NN] = NE;
    }
}

__global__ __launch_bounds__(256) void partition_edges(const int* __restrict__ ei, const float* __restrict__ ev,
                                                       int* __restrict__ bucketFill, int2* __restrict__ ebuf) {
    __shared__ int cnt[BN_BUCK];
    __shared__ int gb[BN_BUCK];
    __shared__ int fill[BN_BUCK];
    int t = threadIdx.x;
    if (t < BN_BUCK) { cnt[t] = 0; fill[t] = 0; }
    __syncthreads();
    int i = blockIdx.x * 1024 + t * 4;
    int4 s4 = *reinterpret_cast<const int4*>(ei + i);
    int4 d4 = *reinterpret_cast<const int4*>(ei + NE + i);
    float4 v4 = *reinterpret_cast<const float4*>(ev + i);
    int b0 = d4.x >> 9, b1 = d4.y >> 9, b2 = d4.z >> 9, b3 = d4.w >> 9;
    atomicAdd(&cnt[b0], 1);
    atomicAdd(&cnt[b1], 1);
    atomicAdd(&cnt[b2], 1);
    atomicAdd(&cnt[b3], 1);
    __syncthreads();
    if (t < BN_BUCK && cnt[t]) gb[t] = atomicAdd(&bucketFill[t], cnt[t]);
    __syncthreads();
    int r;
    r = atomicAdd(&fill[b0], 1); ebuf[gb[b0] + r] = make_int2((s4.x << 9) | (d4.x & 511), __float_as_int(v4.x));
    r = atomicAdd(&fill[b1], 1); ebuf[gb[b1] + r] = make_int2((s4.y << 9) | (d4.y & 511), __float_as_int(v4.y));
    r = atomicAdd(&fill[b2], 1); ebuf[gb[b2] + r] = make_int2((s4.z << 9) | (d4.z & 511), __float_as_int(v4.z));
    r = atomicAdd(&fill[b3], 1); ebuf[gb[b3] + r] = make_int2((s4.w << 9) | (d4.w & 511), __float_as_int(v4.w));
}

__global__ __launch_bounds__(256) void bucket_csr(const int* __restrict__ bucketBase,
                                                  const int2* __restrict__ ebuf,
                                                  int* __restrict__ row_ptr, int2* __restrict__ cp) {
    __shared__ int cnt[512];
    __shared__ int pairs[256];
    int b = blockIdx.x, t = threadIdx.x;
    int beg = bucketBase[b], end = bucketBase[b + 1];
    cnt[t] = 0;
    cnt[t + 256] = 0;
    __syncthreads();
    for (int e = beg + t; e < end; e += 256)
        atomicAdd(&cnt[ebuf[e].x & 511], 1);
    __syncthreads();
    int c0 = cnt[2 * t], c1 = cnt[2 * t + 1];
    int p = c0 + c1;
    pairs[t] = p;
    __syncthreads();
    for (int d = 1; d < 256; d <<= 1) {
        int x = (t >= d) ? pairs[t - d] : 0;
        __syncthreads();
        pairs[t] += x;
        __syncthreads();
    }
    int ep = pairs[t] - p;
    int e0 = ep, e1 = ep + c0;
    int g0 = b * 512 + 2 * t;
    if (g0 < NN) row_ptr[g0] = beg + e0;
    if (g0 + 1 < NN) row_ptr[g0 + 1] = beg + e1;
    __syncthreads();
    cnt[2 * t] = e0;
    cnt[2 * t + 1] = e1;
    __syncthreads();
    for (int e = beg + t; e < end; e += 256) {
        int2 E = ebuf[e];
        int r = atomicAdd(&cnt[E.x & 511], 1);
        cp[beg + r] = make_int2(E.x >> 9, E.y);
    }
}

// ---------------- merged conversions: x->bf16, W1/W2 transpose, W3 pad-transpose ----------------

__global__ __launch_bounds__(256) void prep_all(const float* __restrict__ x,
                                                const float* __restrict__ W1,
                                                const float* __restrict__ W2,
                                                const float* __restrict__ W3,
                                                unsigned short* __restrict__ B0,
                                                unsigned short* __restrict__ Wt1,
                                                unsigned short* __restrict__ Wt2,
                                                unsigned short* __restrict__ Wt3p) {
    int b = blockIdx.x, t = threadIdx.x;
    if (b < 25000) {
        int i = b * 256 + t;
        float4 v = reinterpret_cast<const float4*>(x)[i];
        ushort4 o;
        o.x = f2bf(v.x); o.y = f2bf(v.y); o.z = f2bf(v.z); o.w = f2bf(v.w);
        reinterpret_cast<ushort4*>(B0)[i] = o;
    } else if (b < 25256) {
        int n = b - 25000;
        Wt1[n * 256 + t] = f2bf(W1[t * 256 + n]);
    } else if (b < 25512) {
        int n = b - 25256;
        Wt2[n * 256 + t] = f2bf(W2[t * 256 + n]);
    } else {
        int n = b - 25512;
        Wt3p[n * 256 + t] = (n < NC) ? f2bf(W3[t * NC + n]) : (unsigned short)0;
    }
}

// ---------------- SPMM bf16: one wave per dst row, 8 gathers kept in flight ----------------

__global__ __launch_bounds__(256) void spmm_bf16(const int* __restrict__ rp,
                                                 const int2* __restrict__ cp,
                                                 const unsigned short* __restrict__ H,
                                                 unsigned short* __restrict__ O) {
    int wv = threadIdx.x >> 6;
    int l = threadIdx.x & 63;
    int row = blockIdx.x * 4 + wv;
    if (row >= NN) return;
    int beg = __builtin_amdgcn_readfirstlane(rp[row]);
    int end = __builtin_amdgcn_readfirstlane(rp[row + 1]);
    const ushort4* __restrict__ H4 = reinterpret_cast<const ushort4*>(H);
    float a0 = 0.f, a1 = 0.f, a2 = 0.f, a3 = 0.f;

    int e = beg;
    int efull = beg + ((end - beg) & ~7);
    if (e < efull) {
        int2 m[8];
#pragma unroll
        for (int j = 0; j < 8; ++j) m[j] = cp[e + j];
        e += 8;
        for (; e < efull; e += 8) {
            int2 mn[8];
#pragma unroll
            for (int j = 0; j < 8; ++j) mn[j] = cp[e + j];
            ushort4 hv[8];
#pragma unroll
            for (int j = 0; j < 8; ++j) hv[j] = H4[(size_t)m[j].x * 64 + l];  // 8 in flight
#pragma unroll
            for (int j = 0; j < 8; ++j) {
                float v = __int_as_float(m[j].y);
                a0 += v * bf2f(hv[j].x);
                a1 += v * bf2f(hv[j].y);
                a2 += v * bf2f(hv[j].z);
                a3 += v * bf2f(hv[j].w);
            }
#pragma unroll
            for (int j = 0; j < 8; ++j) m[j] = mn[j];
        }
        {
            ushort4 hv[8];
#pragma unroll
            for (int j = 0; j < 8; ++j) hv[j] = H4[(size_t)m[j].x * 64 + l];
#pragma unroll
            for (int j = 0; j < 8; ++j) {
                float v = __int_as_float(m[j].y);
                a0 += v * bf2f(hv[j].x);
                a1 += v * bf2f(hv[j].y);
                a2 += v * bf2f(hv[j].z);
                a3 += v * bf2f(hv[j].w);
            }
        }
    }
    for (; e < end; ++e) {
        int2 m1 = cp[e];
        ushort4 hv = H4[(size_t)m1.x * 64 + l];
        float v = __int_as_float(m1.y);
        a0 += v * bf2f(hv.x);
        a1 += v * bf2f(hv.y);
        a2 += v * bf2f(hv.z);
        a3 += v * bf2f(hv.w);
    }
    ushort4 o;
    o.x = f2bf(a0); o.y = f2bf(a1); o.z = f2bf(a2); o.w = f2bf(a3);
    reinterpret_cast<ushort4*>(O)[(size_t)row * 64 + l] = o;
}

// ---------------- MFMA GEMM: C[M,256] = A[M,256](bf16) @ Wt[n][k](bf16), opt ReLU, out bf16 ----

#define BM 128
#define BKK 64

__global__ __launch_bounds__(256) void gemm_mfma(const unsigned short* __restrict__ A,
                                                 const unsigned short* __restrict__ Wt,
                                                 unsigned short* __restrict__ C, int M, int relu) {
    __shared__ unsigned short As[BM * BKK];
    __shared__ unsigned short Bs[BM * BKK];
    int tid = threadIdx.x;
    int l = tid & 63;
    int w = tid >> 6;
    int wm = w >> 1, wn = w & 1;
    int bm = blockIdx.x * BM;
    int bn = blockIdx.y * BM;

    f32x4 acc[4][4] = {};

    for (int kt = 0; kt < 4; ++kt) {
        int k0 = kt * BKK;
#pragma unroll
        for (int i = 0; i < 4; ++i) {
            int e = i * 256 + tid;
            int row = e >> 3;
            int c = e & 7;
            int cs = c ^ (row & 7);
            int ga = min(bm + row, M - 1);
            __builtin_amdgcn_global_load_lds(
                (const AS1 u32*)(A + (size_t)ga * 256 + k0 + cs * 8),
                (AS3 u32*)(As + e * 8), 16, 0, 0);
            __builtin_amdgcn_global_load_lds(
                (const AS1 u32*)(Wt + (size_t)(bn + row) * 256 + k0 + cs * 8),
                (AS3 u32*)(Bs + e * 8), 16, 0, 0);
        }
        __syncthreads();
#pragma unroll
        for (int h = 0; h < 2; ++h) {
            short8 av[4], bv[4];
#pragma unroll
            for (int m = 0; m < 4; ++m) {
                int row = wm * 64 + m * 16 + (l & 15);
                int cs = (h * 4 + (l >> 4)) ^ (row & 7);
                av[m] = *(const short8*)(As + row * BKK + cs * 8);
            }
#pragma unroll
            for (int n = 0; n < 4; ++n) {
                int row = wn * 64 + n * 16 + (l & 15);
                int cs = (h * 4 + (l >> 4)) ^ (row & 7);
                bv[n] = *(const short8*)(Bs + row * BKK + cs * 8);
            }
#pragma unroll
            for (int m = 0; m < 4; ++m)
#pragma unroll
                for (int n = 0; n < 4; ++n)
                    acc[m][n] = __builtin_amdgcn_mfma_f32_16x16x32_bf16(av[m], bv[n], acc[m][n], 0, 0, 0);
        }
        __syncthreads();
    }

#pragma unroll
    for (int m = 0; m < 4; ++m)
#pragma unroll
        for (int r = 0; r < 4; ++r) {
            int gr = bm + wm * 64 + m * 16 + (l >> 4) * 4 + r;
            if (gr >= M) continue;
#pragma unroll
            for (int n = 0; n < 4; ++n) {
                int gc = bn + wn * 64 + n * 16 + (l & 15);
                float v = acc[m][n][r];
                if (relu) v = fmaxf(v, 0.f);
                C[(size_t)gr * 256 + gc] = f2bf(v);
            }
        }
}

// ------- GEMM3: Lb[M,40](bf16) = H2[M,256](bf16) @ Wt3p[48][256](bf16) -------

__global__ __launch_bounds__(256) void gemm3_mfma(const unsigned short* __restrict__ H2,
                                                  const unsigned short* __restrict__ Wt3p,
                                                  unsigned short* __restrict__ Lb) {
    int tid = threadIdx.x, l = tid & 63, w = tid >> 6;
    int row0 = blockIdx.x * 64 + w * 16;
    f32x4 acc[3] = {};
    int ra = min(row0 + (l & 15), NN - 1);
    const unsigned short* ap = H2 + (size_t)ra * 256 + (l >> 4) * 8;
#pragma unroll
    for (int kt = 0; kt < 8; ++kt) {
        short8 av = *(const short8*)(ap + kt * 32);
#pragma unroll
        for (int j = 0; j < 3; ++j) {
            const unsigned short* bp = Wt3p + (size_t)(j * 16 + (l & 15)) * 256 + kt * 32 + (l >> 4) * 8;
            short8 bv = *(const short8*)bp;
            acc[j] = __builtin_amdgcn_mfma_f32_16x16x32_bf16(av, bv, acc[j], 0, 0, 0);
        }
    }
#pragma unroll
    for (int j = 0; j < 3; ++j)
#pragma unroll
        for (int r = 0; r < 4; ++r) {
            int gr = row0 + (l >> 4) * 4 + r;
            int gc = j * 16 + (l & 15);
            if (gr < NN && gc < NC) Lb[(size_t)gr * NC + gc] = f2bf(acc[j][r]);
        }
}

// ------- fused: out[row] = log_softmax( sum_e val * Lb[src] ), wave per row, Lb stride 40 -------

__global__ __launch_bounds__(256) void spmm40_lsm(const int* __restrict__ rp,
                                                  const int2* __restrict__ cp,
                                                  const unsigned short* __restrict__ Lb,
                                                  float* __restrict__ out) {
    int wv = threadIdx.x >> 6, l = threadIdx.x & 63;
    int row = blockIdx.x * 4 + wv;
    if (row >= NN) return;
    int beg = __builtin_amdgcn_readfirstlane(rp[row]);
    int end = __builtin_amdgcn_readfirstlane(rp[row + 1]);
    int lc = min(l, NC - 1);
    float acc = 0.f;
    int e = beg;
    int efull = beg + ((end - beg) & ~7);
    if (e < efull) {
        int2 m[8];
#pragma unroll
        for (int j = 0; j < 8; ++j) m[j] = cp[e + j];
        e += 8;
        for (; e < efull; e += 8) {
            int2 mn[8];
#pragma unroll
            for (int j = 0; j < 8; ++j) mn[j] = cp[e + j];
            unsigned short hv[8];
#pragma unroll
            for (int j = 0; j < 8; ++j) hv[j] = Lb[(size_t)m[j].x * NC + lc];
#pragma unroll
            for (int j = 0; j < 8; ++j)
                acc += __int_as_float(m[j].y) * bf2f(hv[j]);
#pragma unroll
            for (int j = 0; j < 8; ++j) m[j] = mn[j];
        }
        {
            unsigned short hv[8];
#pragma unroll
            for (int j = 0; j < 8; ++j) hv[j] = Lb[(size_t)m[j].x * NC + lc];
#pragma unroll
            for (int j = 0; j < 8; ++j)
                acc += __int_as_float(m[j].y) * bf2f(hv[j]);
        }
    }
    for (; e < end; ++e) {
        int2 m1 = cp[e];
        acc += __int_as_float(m1.y) * bf2f(Lb[(size_t)m1.x * NC + lc]);
    }
    float v = (l < NC) ? acc : -INFINITY;
    float mx = v;
    for (int d = 32; d > 0; d >>= 1) mx = fmaxf(mx, __shfl_xor(mx, d));
    float ex = (l < NC) ? expf(v - mx) : 0.f;
    float ssum = ex;
    for (int d = 32; d > 0; d >>= 1) ssum += __shfl_xor(ssum, d);
    float ls = logf(ssum);
    if (l < NC) out[(size_t)row * NC + l] = v - mx - ls;
}

// ---------------- launch ----------------

extern "C" void kernel_launch(void* const* d_in, const int* in_sizes, int n_in,
                              void* d_out, int out_size, void* d_ws, size_t ws_size,
                              hipStream_t stream) {
    const float* x  = (const float*)d_in[0];
    const int*   ei = (const int*)d_in[1];
    const float* ev = (const float*)d_in[2];
    const float* W1 = (const float*)d_in[3];
    const float* W2 = (const float*)d_in[4];
    const float* W3 = (const float*)d_in[5];
    float* out = (float*)d_out;

    char* ws = (char*)d_ws;
    size_t o = 0;
    unsigned short* B0 = (unsigned short*)(ws + o); o += (size_t)NN * FD * 2;   // 51.2 MB
    unsigned short* B1 = (unsigned short*)(ws + o); o += (size_t)NN * FD * 2;   // 51.2 MB (aliases ebuf)
    unsigned short* Lb = (unsigned short*)(ws + o); o += (size_t)NN * NC * 2;   // 8 MB
    int2*  cp          = (int2*)(ws + o);           o += (size_t)NE * 8;        // 25.6 MB
    int*   row_ptr     = (int*)(ws + o);            o += 400128;
    int*   gcount      = (int*)(ws + o);            o += 1024;
    int*   bucketBase  = (int*)(ws + o);            o += 1024;
    int*   bucketFill  = (int*)(ws + o);            o += 1024;
    unsigned short* Wt1  = (unsigned short*)(ws + o); o += 256 * 256 * 2;
    unsigned short* Wt2  = (unsigned short*)(ws + o); o += 256 * 256 * 2;
    unsigned short* Wt3p = (unsigned short*)(ws + o); o += 48 * 256 * 2;

    int2* ebuf = (int2*)B1;   // lifetime: partition_edges..bucket_csr, before B1's first write

    const int EB     = NE / 1024;                 // 3125
    const int RGRID  = (NN + 3) / 4;              // 25000
    const int GXM    = (NN + BM - 1) / BM;        // 782
    const int G3     = (NN + 63) / 64;            // 1563

    // binned CSR build
    hipMemsetAsync(gcount, 0, BN_BUCK * sizeof(int), stream);
    bucket_count<<<EB, 256, 0, stream>>>(ei + NE, gcount);
    bucket_scan<<<1, 256, 0, stream>>>(gcount, bucketBase, bucketFill, row_ptr);
    partition_edges<<<EB, 256, 0, stream>>>(ei, ev, bucketFill, ebuf);
    bucket_csr<<<BN_BUCK, 256, 0, stream>>>(bucketBase, ebuf, row_ptr, cp);

    // conversions (one launch)
    prep_all<<<25560, 256, 0, stream>>>(x, W1, W2, W3, B0, Wt1, Wt2, Wt3p);

    // Layer 1: spmm(x) @ W1, relu
    spmm_bf16<<<RGRID, 256, 0, stream>>>(row_ptr, cp, B0, B1);
    gemm_mfma<<<dim3(GXM, 2), 256, 0, stream>>>(B1, Wt1, B0, NN, 1);

    // Layer 2
    spmm_bf16<<<RGRID, 256, 0, stream>>>(row_ptr, cp, B0, B1);
    gemm_mfma<<<dim3(GXM, 2), 256, 0, stream>>>(B1, Wt2, B0, NN, 1);

    // Layer 3 (reordered): Lb = H2 @ W3 (bf16, 40-wide), then fused spmm40 + log_softmax
    gemm3_mfma<<<G3, 256, 0, stream>>>(B0, Wt3p, Lb);
    spmm40_lsm<<<RGRID, 256, 0, stream>>>(row_ptr, cp, Lb, out);
}